// Round 2
// baseline (240.319 us; speedup 1.0000x reference)
//
#include <hip/hip_runtime.h>
#include <math.h>

// RX gate on qubit 5 of 12, batch 4096 states of dim 4096.
// out_re[i] = c*sr[i] + s*si[i^64];  out_im[i] = c*si[i] - s*sr[i^64]
// (M = c*I - i*s*X_hyd is symmetric; X_hyd is the bit-6 flip permutation.)
//
// v3: - plain (write-back) stores instead of nontemporal: NT's anti-pollution
//       rationale is void (harness fills thrash L3 anyway) and the NT path is
//       the one constant across two equally-slow variants.
//     - 4 pairs per thread, all 16 loads issued before any use -> deep MLP,
//       grid = 2048 blocks = exactly one co-resident round (no block churn).
// Pair decomposition: in f32x4-index space the partner is V^16; thread owns
// (i, i+16) with i = p + (p & ~15) (bit4 of vec index forced to 0), so all
// butterfly cross terms are thread-local registers. Lanes 0-15 of a wave
// touch 256B-contiguous segments -> fully coalesced, every fetched byte used.

#define NQ_N 4096
#define NQ_BATCH 4096

typedef float f32x4 __attribute__((ext_vector_type(4)));

// total f32x4 vecs = 2^22 ; pairs = 2^21 ; 4 pairs/thread -> 2^19 threads
#define PAIRS_LOG2 21u
#define PPT 4u
#define THREADS (1u << (PAIRS_LOG2 - 2))   // 2^19
#define KOFF (1u << (PAIRS_LOG2 - 2))      // pair-slice stride = 2^19

__global__ __launch_bounds__(256)
void rx_pair4_kernel(const f32x4* __restrict__ sr,
                     const f32x4* __restrict__ si,
                     const float* __restrict__ theta_p,
                     f32x4* __restrict__ out_re,
                     f32x4* __restrict__ out_im)
{
    const float half = 0.5f * theta_p[0];
    const float c = cosf(half);
    const float s = sinf(half);

    const unsigned u = blockIdx.x * blockDim.x + threadIdx.x; // base pair id

    // 4 pair ids, one per dense slice of the pair space
    unsigned iv[PPT], jv[PPT];
#pragma unroll
    for (unsigned k = 0; k < PPT; ++k) {
        const unsigned p = u + k * KOFF;
        const unsigned i = p + (p & ~15u);  // vec index with bit4 = 0
        iv[k] = i;
        jv[k] = i + 16u;
    }

    // issue all 16 loads before any use (vmcnt-pipelined)
    f32x4 rA[PPT], rB[PPT], mA[PPT], mB[PPT];
#pragma unroll
    for (unsigned k = 0; k < PPT; ++k) rA[k] = sr[iv[k]];
#pragma unroll
    for (unsigned k = 0; k < PPT; ++k) rB[k] = sr[jv[k]];
#pragma unroll
    for (unsigned k = 0; k < PPT; ++k) mA[k] = si[iv[k]];
#pragma unroll
    for (unsigned k = 0; k < PPT; ++k) mB[k] = si[jv[k]];

#pragma unroll
    for (unsigned k = 0; k < PPT; ++k) {
        f32x4 reA, imA, reB, imB;
#pragma unroll
        for (int q = 0; q < 4; ++q) {
            reA[q] = fmaf(c, rA[k][q],  s * mB[k][q]);
            imA[q] = fmaf(c, mA[k][q], -s * rB[k][q]);
            reB[q] = fmaf(c, rB[k][q],  s * mA[k][q]);
            imB[q] = fmaf(c, mB[k][q], -s * rA[k][q]);
        }
        out_re[iv[k]] = reA;
        out_im[iv[k]] = imA;
        out_re[jv[k]] = reB;
        out_im[jv[k]] = imB;
    }
}

extern "C" void kernel_launch(void* const* d_in, const int* in_sizes, int n_in,
                              void* d_out, int out_size, void* d_ws, size_t ws_size,
                              hipStream_t stream)
{
    const f32x4* sr = (const f32x4*)d_in[0];
    const f32x4* si = (const f32x4*)d_in[1];
    const float* th = (const float*)d_in[2];

    f32x4* out_re = (f32x4*)d_out;
    f32x4* out_im = out_re + ((size_t)NQ_BATCH * NQ_N / 4);

    const unsigned block = 256;
    const unsigned grid = THREADS / block;   // 2048 blocks = 1 resident round

    rx_pair4_kernel<<<grid, block, 0, stream>>>(sr, si, th, out_re, out_im);
}

// Round 3
// 236.668 us; speedup vs baseline: 1.0154x; 1.0154x over previous
//
#include <hip/hip_runtime.h>
#include <math.h>

// RX gate on qubit 5 of 12, batch 4096 states of dim 4096.
// out_re[i] = c*sr[i] + s*si[i^64];  out_im[i] = c*si[i] - s*sr[i^64]
// (M = c*I - i*s*X_hyd is symmetric; X_hyd is the bit-6 flip permutation.)
//
// v4: persistent software-pipelined waves. Evidence so far: burst-MLP depth
// (2/8/16 loads in flight) and access pattern don't move the needle; kernel
// sits at ~3.3 TB/s logical with HBM unsaturated (fills hit 6.7 TB/s) ->
// read-latency bound with waves that die after one round. This version keeps
// every wave alive for 4 rounds with the NEXT round's 4 loads always in
// flight while the current round computes+stores (the copy-kernel shape).
//  - grid 2048 x 256 = exactly 32 waves/CU resident, no churn
//  - block b owns pairs [b*1024,(b+1)*1024): 32KB contiguous per array
//  - NT stores restored (v2 vs v3: worth a few %)
//  - __launch_bounds__(256,8) caps VGPRs at 64 so all 32 waves/CU fit

#define NQ_N 4096
#define NQ_BATCH 4096

typedef float f32x4 __attribute__((ext_vector_type(4)));

#define PPT 4u                     // rounds (pairs) per thread
#define BLK 256u
#define GRID 2048u                 // 2048*256*4 = 2^21 pairs total

__global__ __launch_bounds__(BLK, 8)
void rx_pipe_kernel(const f32x4* __restrict__ sr,
                    const f32x4* __restrict__ si,
                    const float* __restrict__ theta_p,
                    f32x4* __restrict__ out_re,
                    f32x4* __restrict__ out_im)
{
    const float half = 0.5f * theta_p[0];
    const float c = cosf(half);
    const float s = sinf(half);

    // block-contiguous mapping: pair p = b*1024 + k*256 + tid
    const unsigned base = blockIdx.x * (BLK * PPT) + threadIdx.x;

    // indices for round k: i = p + (p & ~15)  (vec index with bit4 = 0)
    unsigned i0, j0;
    {
        const unsigned p = base;
        i0 = p + (p & ~15u);
        j0 = i0 + 16u;
    }

    // prologue: round-0 loads
    f32x4 rA = sr[i0];
    f32x4 rB = sr[j0];
    f32x4 mA = si[i0];
    f32x4 mB = si[j0];

#pragma unroll
    for (unsigned k = 0; k < PPT; ++k) {
        // issue next round's loads BEFORE using this round's data
        unsigned i1 = 0, j1 = 0;
        f32x4 rA1, rB1, mA1, mB1;
        if (k + 1 < PPT) {
            const unsigned p = base + (k + 1) * BLK;
            i1 = p + (p & ~15u);
            j1 = i1 + 16u;
            rA1 = sr[i1];
            rB1 = sr[j1];
            mA1 = si[i1];
            mB1 = si[j1];
        }

        f32x4 reA, imA, reB, imB;
#pragma unroll
        for (int q = 0; q < 4; ++q) {
            reA[q] = fmaf(c, rA[q],  s * mB[q]);
            imA[q] = fmaf(c, mA[q], -s * rB[q]);
            reB[q] = fmaf(c, rB[q],  s * mA[q]);
            imB[q] = fmaf(c, mB[q], -s * rA[q]);
        }

        __builtin_nontemporal_store(reA, out_re + i0);
        __builtin_nontemporal_store(imA, out_im + i0);
        __builtin_nontemporal_store(reB, out_re + j0);
        __builtin_nontemporal_store(imB, out_im + j0);

        // rotate pipeline registers
        i0 = i1; j0 = j1;
        rA = rA1; rB = rB1; mA = mA1; mB = mB1;
    }
}

extern "C" void kernel_launch(void* const* d_in, const int* in_sizes, int n_in,
                              void* d_out, int out_size, void* d_ws, size_t ws_size,
                              hipStream_t stream)
{
    const f32x4* sr = (const f32x4*)d_in[0];
    const f32x4* si = (const f32x4*)d_in[1];
    const float* th = (const float*)d_in[2];

    f32x4* out_re = (f32x4*)d_out;
    f32x4* out_im = out_re + ((size_t)NQ_BATCH * NQ_N / 4);

    rx_pipe_kernel<<<GRID, BLK, 0, stream>>>(sr, si, th, out_re, out_im);
}

// Round 4
// 225.950 us; speedup vs baseline: 1.0636x; 1.0474x over previous
//
#include <hip/hip_runtime.h>
#include <math.h>

// RX gate on qubit 5 of 12, batch 4096 states of dim 4096.
// out_re[i] = c*sr[i] + s*si[i^64];  out_im[i] = c*si[i] - s*sr[i^64]
// (M = c*I - i*s*X_hyd is symmetric; X_hyd is the bit-6 flip permutation.)
//
// v5: v2 shape (pair-per-thread, 8 loads in flight, grid 4096, NT stores)
// with ONE change: all input loads are NONTEMPORAL. Across v1-v4, structure
// (shuffle vs pair, MLP depth 2/8/16, grid 16K/2K, persistent pipeline) is
// proven irrelevant: all pinned at ~80us, traffic compulsory-exact, waves
// resident-but-stalled. Hypothesis: single-use streaming reads allocating
// into the 4MiB/XCD L2 cause continuous eviction/tag churn in the same path
// the read returns use; nt loads bypass LRU allocation like the NT stores
// and the 6.7TB/s fills already do.

#define NQ_N 4096
#define NQ_BATCH 4096

typedef float f32x4 __attribute__((ext_vector_type(4)));

// total f32x4 vecs = 4096*4096/4 = 2^22 ; pairs = 2^21 ; 2 pairs/thread
#define TOTAL_PAIRS (1u << 21)
#define PAIR_OFFSET (1u << 20)   // second pair = first + half the pair space

__global__ __launch_bounds__(256)
void rx_nt_kernel(const f32x4* __restrict__ sr,
                  const f32x4* __restrict__ si,
                  const float* __restrict__ theta_p,
                  f32x4* __restrict__ out_re,
                  f32x4* __restrict__ out_im)
{
    const float half = 0.5f * theta_p[0];
    const float c = cosf(half);
    const float s = sinf(half);

    const unsigned u = blockIdx.x * blockDim.x + threadIdx.x; // pair id (lo half)

    const unsigned p0 = u;
    const unsigned p1 = u + PAIR_OFFSET;

    // pair p -> vec index i with bit4 forced to 0: i = p + (p & ~15)
    const unsigned i0 = p0 + (p0 & ~15u);
    const unsigned j0 = i0 + 16;
    const unsigned i1 = p1 + (p1 & ~15u);
    const unsigned j1 = i1 + 16;

    // 8 independent NONTEMPORAL loads — issued before any use
    const f32x4 rA = __builtin_nontemporal_load(sr + i0);
    const f32x4 rB = __builtin_nontemporal_load(sr + j0);
    const f32x4 mA = __builtin_nontemporal_load(si + i0);
    const f32x4 mB = __builtin_nontemporal_load(si + j0);
    const f32x4 rC = __builtin_nontemporal_load(sr + i1);
    const f32x4 rD = __builtin_nontemporal_load(sr + j1);
    const f32x4 mC = __builtin_nontemporal_load(si + i1);
    const f32x4 mD = __builtin_nontemporal_load(si + j1);

    f32x4 reA, imA, reB, imB, reC, imC, reD, imD;
#pragma unroll
    for (int k = 0; k < 4; ++k) {
        reA[k] = fmaf(c, rA[k],  s * mB[k]);
        imA[k] = fmaf(c, mA[k], -s * rB[k]);
        reB[k] = fmaf(c, rB[k],  s * mA[k]);
        imB[k] = fmaf(c, mB[k], -s * rA[k]);
        reC[k] = fmaf(c, rC[k],  s * mD[k]);
        imC[k] = fmaf(c, mC[k], -s * rD[k]);
        reD[k] = fmaf(c, rD[k],  s * mC[k]);
        imD[k] = fmaf(c, mD[k], -s * rC[k]);
    }

    __builtin_nontemporal_store(reA, out_re + i0);
    __builtin_nontemporal_store(imA, out_im + i0);
    __builtin_nontemporal_store(reB, out_re + j0);
    __builtin_nontemporal_store(imB, out_im + j0);
    __builtin_nontemporal_store(reC, out_re + i1);
    __builtin_nontemporal_store(imC, out_im + i1);
    __builtin_nontemporal_store(reD, out_re + j1);
    __builtin_nontemporal_store(imD, out_im + j1);
}

extern "C" void kernel_launch(void* const* d_in, const int* in_sizes, int n_in,
                              void* d_out, int out_size, void* d_ws, size_t ws_size,
                              hipStream_t stream)
{
    const f32x4* sr = (const f32x4*)d_in[0];
    const f32x4* si = (const f32x4*)d_in[1];
    const float* th = (const float*)d_in[2];

    f32x4* out_re = (f32x4*)d_out;
    f32x4* out_im = out_re + ((size_t)NQ_BATCH * NQ_N / 4);

    const unsigned threads = TOTAL_PAIRS / 2;  // 2 pairs per thread -> 2^20
    const unsigned block = 256;
    const unsigned grid = threads / block;     // 4096

    rx_nt_kernel<<<grid, block, 0, stream>>>(sr, si, th, out_re, out_im);
}